// Round 15
// baseline (95.049 us; speedup 1.0000x reference)
//
#include <hip/hip_runtime.h>

#define Bsz 4
#define Cch 64
#define Hh 128
#define Ww 128
#define NOFF 18      // 2*3*3 offset channels
#define CK 576       // 64*9 reduction length for deform einsum (K = tap*64 + c)
#define SMPAD 324    // smp row stride (u16) for the 5-tap round (320 + pad)

typedef __attribute__((ext_vector_type(8))) short short8;
typedef __attribute__((ext_vector_type(4))) float floatx4;

__device__ __forceinline__ unsigned short f2bf(float f) {
    union { float f; unsigned u; } v; v.f = f;
    unsigned r = v.u + 0x7fff + ((v.u >> 16) & 1);   // round-to-nearest-even
    return (unsigned short)(r >> 16);
}
__device__ __forceinline__ float bflo(unsigned d) {
    union { unsigned u; float f; } v; v.u = d << 16; return v.f;
}
__device__ __forceinline__ float bfhi(unsigned d) {
    union { unsigned u; float f; } v; v.u = d & 0xffff0000u; return v.f;
}
__device__ __forceinline__ unsigned cvtpk(float lo, float hi) {   // {bf16(lo), bf16(hi)<<16}
    unsigned r;
    asm("v_cvt_pk_bf16_f32 %0, %1, %2" : "=v"(r) : "v"(lo), "v"(hi));
    return r;
}

// ---------------------------------------------------------------------------
// Prep kernel.
//   blocks 0..511  : build xpair[b][h*w][128ch] u32 = {bf16 v(pos,c), bf16 v(pos+1,c)}
//   blocks 512..655: deform weight w[oc][c][tap] -> wbf[oc][tap*64+c] bf16
//   blocks 656..799: offset weight wo[oc][ci][tap] -> w9[tap][32ocp][128ci] bf16
__global__ __launch_bounds__(256) void prep(const float* __restrict__ x,
                                            const float* __restrict__ ref,
                                            const float* __restrict__ wo,
                                            const float* __restrict__ w,
                                            unsigned* __restrict__ xpair,
                                            unsigned short* __restrict__ w9,
                                            unsigned short* __restrict__ wbf) {
    __shared__ unsigned tile[64][130];   // [cpair][px]; stride 130 u32
    int bid = blockIdx.x;
    int tid = threadIdx.x;
    if (bid < 512) {
        int b = bid >> 7;
        int h = bid & 127;
        int px2 = tid & 63;              // pixel pair: px = 2*px2, 2*px2+1
        int cg = tid >> 6;               // 32-channel group
        const float* xb = x + ((size_t)b << 20) + (h << 7) + (px2 << 1);
        const float* rb = ref + ((size_t)b << 20) + (h << 7) + (px2 << 1);
#pragma unroll
        for (int j = 0; j < 16; ++j) {
            int c0 = cg * 32 + 2 * j;
            const float* s = (c0 < 64) ? xb : rb;
            int cl = c0 & 63;
            float2 va = *(const float2*)(s + ((size_t)cl << 14));
            float2 vb = *(const float2*)(s + ((size_t)(cl + 1) << 14));
            unsigned w0 = (unsigned)f2bf(va.x) | ((unsigned)f2bf(vb.x) << 16);
            unsigned w1 = (unsigned)f2bf(va.y) | ((unsigned)f2bf(vb.y) << 16);
            *(uint2*)(&tile[c0 >> 1][px2 << 1]) = make_uint2(w0, w1);
        }
        __syncthreads();
#pragma unroll
        for (int it = 0; it < 16; ++it) {
            int idx = it * 256 + tid;
            int cq5 = idx & 31;          // 4-channel group
            int pos = idx >> 5;          // 0..127
            int posn = min(pos + 1, 127);
            unsigned t0 = tile[2 * cq5][pos], t0n = tile[2 * cq5][posn];
            unsigned t1 = tile[2 * cq5 + 1][pos], t1n = tile[2 * cq5 + 1][posn];
            uint4 o;
            o.x = (t0 & 0xffffu) | (t0n << 16);
            o.y = (t0 >> 16) | (t0n & 0xffff0000u);
            o.z = (t1 & 0xffffu) | (t1n << 16);
            o.w = (t1 >> 16) | (t1n & 0xffff0000u);
            *(uint4*)(xpair + (((size_t)(b << 14) + (h << 7) + pos) << 7) + (cq5 << 2)) = o;
        }
    } else if (bid < 656) {
        int t = (bid - 512) * 256 + tid;
        if (t < Cch * CK) {
            int oc = t / CK;
            int rem = t % CK;
            int k = rem >> 6, c = rem & 63;
            wbf[t] = f2bf(w[(oc * Cch + c) * 9 + k]);
        }
    } else {
        int t = (bid - 656) * 256 + tid;
        if (t < 9 * 32 * 128) {
            int ci = t & 127, ocp = (t >> 7) & 31, tap = t >> 12;
            w9[t] = (ocp < NOFF) ? f2bf(wo[(ocp * 128 + ci) * 9 + tap]) : (unsigned short)0;
        }
    }
}

// ---------------------------------------------------------------------------
// Fused kernel, 16-px blocks, ~15.5 KB LDS -> high occupancy.
// A0 : stage tile3[3][18][128] bf16 from xpair lows (coalesced, XOR-swizzled).
// A1 : offset MFMA; 4 waves = 2 oc-tiles x 2 ci-halves -> red.
// FIN: kh==0 waves finalize offsets + corner weights/meta (alias over tile3).
// B/B1 K-split: round0 = taps 0-4 (gather -> smp -> 10 MFMA), round1 = taps
//      5-8 (8 MFMA); round-1 gather loads issued BEFORE round-0 MFMA.
__global__ __launch_bounds__(256, 6) void fused_align(
        const unsigned* __restrict__ xpair,
        const unsigned short* __restrict__ w9,
        const unsigned short* __restrict__ wbf,
        const float* __restrict__ bias,
        float* __restrict__ out) {
    __shared__ union {
        unsigned short tile3[3 * 18 * 128];                   // 13824 B
        struct {
            unsigned short smp[16][SMPAD];                    // 10368 B
            float4 wts[144];                                  // 2304 B
            int2 meta[144];                                   // 1152 B
        } bb;                                                 // 13824 B
    } u;
    __shared__ float red[2][64][4];                           // 2 KB

    int bi0 = blockIdx.x;
    int bi = ((bi0 & 7) << 9) | (bi0 >> 3);   // XCD swizzle (4096 = 8*512)
    int b = bi >> 10;
    int rem = bi & 1023;
    int h = rem >> 3;
    int w0 = (rem & 7) << 4;
    int tid = threadIdx.x;
    int wv = tid >> 6, lane = tid & 63;
    int to = wv & 1;          // oc tile (offset conv)
    int kh = wv >> 1;         // ci half (0: x, 1: ref)
    int r16 = lane & 15;
    int g = lane >> 4;

    const unsigned* xp32 = xpair + ((size_t)b << 21);   // b * 16384 pos * 128 u32

    float bias4[4] = {0.f, 0.f, 0.f, 0.f};
    if (kh == 0) {
#pragma unroll
        for (int r = 0; r < 4; ++r) {
            int oc = to * 16 + g * 4 + r;
            if (oc < NOFF) bias4[r] = bias[oc];
        }
    }

    // ---- Phase A0: stage 54 positions x 256B from xpair lows ----
#pragma unroll
    for (int it = 0; it < 7; ++it) {
        int idx = it * 256 + tid;
        if (idx < 1728) {
            int cq4 = idx & 31;              // 4-channel group
            int pos = idx >> 5;              // row*18 + xx
            int row = pos / 18, xx = pos % 18;
            int yy = h + row - 1, xg = w0 + xx - 1;
            uint4 q = make_uint4(0u, 0u, 0u, 0u);
            if ((unsigned)yy < (unsigned)Hh && (unsigned)xg < (unsigned)Ww)
                q = *(const uint4*)(xp32 + (((yy << 7) + xg) << 7) + (cq4 << 2));
            unsigned p0 = (q.x & 0xffffu) | (q.y << 16);
            unsigned p1 = (q.z & 0xffffu) | (q.w << 16);
            int ci0 = cq4 << 2;
            *(uint2*)(&u.tile3[(pos << 7) + (ci0 ^ ((xx & 7) << 3))]) = make_uint2(p0, p1);
        }
    }
    __syncthreads();

    // ---- Phase A1: offset conv MFMA (9 taps x 2 per wave) ----
    floatx4 accA = {0.f, 0.f, 0.f, 0.f};
#pragma unroll
    for (int tap = 0; tap < 9; ++tap) {
        int dy = tap / 3, dx = tap % 3;
        int xxr = r16 + dx;                              // 0..17
        const unsigned short* brow = &u.tile3[(dy * 18 + xxr) << 7];
        int sw = (xxr & 7) << 3;
        const unsigned short* arow = w9 + ((size_t)(tap * 32 + to * 16 + r16) << 7) + kh * 64;
#pragma unroll
        for (int kk = 0; kk < 2; ++kk) {
            int cb = kh * 64 + kk * 32 + g * 8;
            short8 bb = *(const short8*)(brow + (cb ^ sw));
            short8 a = *(const short8*)(arow + kk * 32 + g * 8);
            accA = __builtin_amdgcn_mfma_f32_16x16x32_bf16(a, bb, accA, 0, 0, 0);
        }
    }
    if (kh == 1) {
#pragma unroll
        for (int r = 0; r < 4; ++r) red[to][lane][r] = accA[r];
    }
    __syncthreads();

    // ---- FIN: offsets -> corner weights + row byte-offsets (alias tile3) ----
    if (kh == 0 && (to == 0 || g == 0)) {
        float vout[4];
#pragma unroll
        for (int r = 0; r < 4; ++r) {
            float v = accA[r] + red[to][lane][r] + bias4[r];
            vout[r] = fminf(fmaxf(v, -10.0f), 10.0f);
        }
        int ntap = (to == 0) ? 2 : 1;
        int kbase = (to * 16 + g * 4) >> 1;
        int p = r16;
#pragma unroll
        for (int t = 0; t < 2; ++t) {
            if (t < ntap) {
                int k = kbase + t;
                float dyo = vout[2 * t], dxo = vout[2 * t + 1];
                int ky = k / 3, kx = k % 3;
                float ys = (float)(h - 1 + ky) + dyo;
                float xs = (float)(w0 + p - 1 + kx) + dxo;
                float fy = floorf(ys), fx = floorf(xs);
                int iy0 = (int)fy, ix0 = (int)fx;
                float ty = ys - fy, tx = xs - fx;
                float wy0 = (1.f - ty) * (((unsigned)iy0 < (unsigned)Hh) ? 1.f : 0.f);
                float wy1 = ty         * (((unsigned)(iy0 + 1) < (unsigned)Hh) ? 1.f : 0.f);
                float wx0 = (1.f - tx) * (((unsigned)ix0 < (unsigned)Ww) ? 1.f : 0.f);
                float wx1 = tx         * (((unsigned)(ix0 + 1) < (unsigned)Ww) ? 1.f : 0.f);
                int ixb  = min(max(ix0, 0), Ww - 2);
                int iy0c = min(max(iy0, 0), Hh - 1);
                int iy1c = min(max(iy0 + 1, 0), Hh - 1);
                bool s0v = (min(max(ix0, 0), Ww - 1) != ixb);
                bool s1v = (min(max(ix0 + 1, 0), Ww - 1) != ixb);
                float w00 = wy0 * wx0, w01 = wy0 * wx1, w10 = wy1 * wx0, w11 = wy1 * wx1;
                float A  = (s0v ? 0.f : w00) + (s1v ? 0.f : w01);   // (y0, ixb)
                float Bw = (s0v ? w00 : 0.f) + (s1v ? w01 : 0.f);   // (y0, ixb+1)
                float Cw = (s0v ? 0.f : w10) + (s1v ? 0.f : w11);   // (y1, ixb)
                float Dw = (s0v ? w10 : 0.f) + (s1v ? w11 : 0.f);   // (y1, ixb+1)
                u.bb.wts[p * 9 + k] = make_float4(A, Bw, Cw, Dw);
                u.bb.meta[p * 9 + k] = make_int2(((iy0c << 7) + ixb) << 9,
                                                 ((iy1c << 7) + ixb) << 9);
            }
        }
    }
    __syncthreads();   // wts/meta ready (tile3 dead)

    // ---- Phase B/B1: K-split, cross-round pipelined ----
    int p0 = tid >> 4, cq = tid & 15;
    const char* xbB = (const char*)xpair + ((size_t)b << 23) + cq * 16;
    const short8* ap = (const short8*)(wbf + (size_t)(wv * 16 + r16) * CK + g * 8);
    const unsigned short* bbase = &u.bb.smp[r16][g * 8];
    floatx4 acc = {0.f, 0.f, 0.f, 0.f};

#define GLD(k, q0, q1)                                                                \
        { int2 mm = u.bb.meta[p0 * 9 + (k)];                                          \
          q0 = *(const uint4*)(xbB + mm.x);                                           \
          q1 = *(const uint4*)(xbB + mm.y); }
#define CPW(k, slot, q0, q1)                                                          \
        { float4 wt = u.bb.wts[p0 * 9 + (k)];                                         \
          float s0 = bflo(q0.x)*wt.x + bfhi(q0.x)*wt.y + bflo(q1.x)*wt.z + bfhi(q1.x)*wt.w; \
          float s1 = bflo(q0.y)*wt.x + bfhi(q0.y)*wt.y + bflo(q1.y)*wt.z + bfhi(q1.y)*wt.w; \
          float s2 = bflo(q0.z)*wt.x + bfhi(q0.z)*wt.y + bflo(q1.z)*wt.z + bfhi(q1.z)*wt.w; \
          float s3 = bflo(q0.w)*wt.x + bfhi(q0.w)*wt.y + bflo(q1.w)*wt.z + bfhi(q1.w)*wt.w; \
          *(uint2*)(&u.bb.smp[p0][(slot) * 64 + cq * 4]) =                            \
              make_uint2(cvtpk(s0, s1), cvtpk(s2, s3)); }

    // round 0: taps 0..4 -> smp slots 0..4
    {
        uint4 a0, a1, b0, b1, c0, c1, d0, d1, e0, e1;
        GLD(0, a0, a1)
        GLD(1, b0, b1)
        GLD(2, c0, c1)
        GLD(3, d0, d1)
        GLD(4, e0, e1)
        CPW(0, 0, a0, a1)
        CPW(1, 1, b0, b1)
        CPW(2, 2, c0, c1)
        CPW(3, 3, d0, d1)
        CPW(4, 4, e0, e1)
    }
    __syncthreads();

    // early-issue round-1 gather loads (land under round-0 MFMA + barrier)
    uint4 f0, f1, g0, g1, h0, h1, i0, i1;
    GLD(5, f0, f1)
    GLD(6, g0, g1)
    GLD(7, h0, h1)
    GLD(8, i0, i1)

    // round-0 deform MFMA: K slots 0..9 (taps 0..4)
#pragma unroll
    for (int kk = 0; kk < 10; ++kk) {
        short8 a = ap[kk * 4];
        short8 v = *(const short8*)(bbase + kk * 32);
        acc = __builtin_amdgcn_mfma_f32_16x16x32_bf16(a, v, acc, 0, 0, 0);
    }
    __syncthreads();

    // round-1 sample pack: taps 5..8 -> smp slots 0..3
    CPW(5, 0, f0, f1)
    CPW(6, 1, g0, g1)
    CPW(7, 2, h0, h1)
    CPW(8, 3, i0, i1)
    __syncthreads();

    // round-1 deform MFMA: K slots 10..17 (taps 5..8)
#pragma unroll
    for (int kk = 0; kk < 8; ++kk) {
        short8 a = ap[(10 + kk) * 4];
        short8 v = *(const short8*)(bbase + kk * 32);
        acc = __builtin_amdgcn_mfma_f32_16x16x32_bf16(a, v, acc, 0, 0, 0);
    }
#undef GLD
#undef CPW

    size_t obase = ((size_t)(b * Cch + wv * 16 + g * 4)) << 14;
    int hw = (h << 7) + w0 + r16;
#pragma unroll
    for (int r = 0; r < 4; ++r)
        out[obase + ((size_t)r << 14) + hw] = acc[r];
}

// ---------------------------------------------------------------------------
extern "C" void kernel_launch(void* const* d_in, const int* in_sizes, int n_in,
                              void* d_out, int out_size, void* d_ws, size_t ws_size,
                              hipStream_t stream) {
    const float* x      = (const float*)d_in[0];
    const float* ref    = (const float*)d_in[1];
    const float* wo     = (const float*)d_in[2];
    const float* bias   = (const float*)d_in[3];
    const float* weight = (const float*)d_in[4];
    float* out = (float*)d_out;

    unsigned short* w9  = (unsigned short*)d_ws;                      // 72 KB
    unsigned short* wbf = (unsigned short*)((char*)d_ws + 262144);    // 72 KB
    unsigned* xpair     = (unsigned*)((char*)d_ws + 524288);          // 33.5 MB

    hipLaunchKernelGGL(prep, dim3(800), dim3(256), 0, stream,
                       x, ref, wo, weight, xpair, w9, wbf);
    hipLaunchKernelGGL(fused_align, dim3(4096), dim3(256), 0, stream,
                       xpair, w9, wbf, bias, out);
}

// Round 16
// 79.659 us; speedup vs baseline: 1.1932x; 1.1932x over previous
//
#include <hip/hip_runtime.h>

#define Bsz 4
#define Cch 64
#define Hh 128
#define Ww 128
#define NOFF 18      // 2*3*3 offset channels
#define CK 576       // 64*9 reduction length for deform einsum (K = k*64 + c)
#define CKPAD 580    // smp row stride (bf16): 1160B

typedef __attribute__((ext_vector_type(8))) short short8;
typedef __attribute__((ext_vector_type(4))) float floatx4;

__device__ __forceinline__ unsigned short f2bf(float f) {
    union { float f; unsigned u; } v; v.f = f;
    unsigned r = v.u + 0x7fff + ((v.u >> 16) & 1);   // round-to-nearest-even
    return (unsigned short)(r >> 16);
}
__device__ __forceinline__ float bflo(unsigned d) {
    union { unsigned u; float f; } v; v.u = d << 16; return v.f;
}
__device__ __forceinline__ float bfhi(unsigned d) {
    union { unsigned u; float f; } v; v.u = d & 0xffff0000u; return v.f;
}
__device__ __forceinline__ unsigned cvtpk(float lo, float hi) {   // {bf16(lo), bf16(hi)<<16}
    unsigned r;
    asm("v_cvt_pk_bf16_f32 %0, %1, %2" : "=v"(r) : "v"(lo), "v"(hi));
    return r;
}

// ---------------------------------------------------------------------------
// Prep kernel.
//   blocks 0..511  : build xpair[b][h*w][128ch] u32 = {bf16 v(pos,c), bf16 v(pos+1,c)}
//   blocks 512..655: deform weight w[oc][c][tap] -> wbf[oc][tap*64+c] bf16
//   blocks 656..799: offset weight wo[oc][ci][tap] -> w9[tap][32ocp][128ci] bf16
__global__ __launch_bounds__(256) void prep(const float* __restrict__ x,
                                            const float* __restrict__ ref,
                                            const float* __restrict__ wo,
                                            const float* __restrict__ w,
                                            unsigned* __restrict__ xpair,
                                            unsigned short* __restrict__ w9,
                                            unsigned short* __restrict__ wbf) {
    __shared__ unsigned tile[64][130];   // [cpair][px]; stride 130 u32
    int bid = blockIdx.x;
    int tid = threadIdx.x;
    if (bid < 512) {
        int b = bid >> 7;
        int h = bid & 127;
        int px2 = tid & 63;              // pixel pair: px = 2*px2, 2*px2+1
        int cg = tid >> 6;               // 32-channel group
        const float* xb = x + ((size_t)b << 20) + (h << 7) + (px2 << 1);
        const float* rb = ref + ((size_t)b << 20) + (h << 7) + (px2 << 1);
#pragma unroll
        for (int j = 0; j < 16; ++j) {
            int c0 = cg * 32 + 2 * j;
            const float* s = (c0 < 64) ? xb : rb;
            int cl = c0 & 63;
            float2 va = *(const float2*)(s + ((size_t)cl << 14));
            float2 vb = *(const float2*)(s + ((size_t)(cl + 1) << 14));
            unsigned w0 = (unsigned)f2bf(va.x) | ((unsigned)f2bf(vb.x) << 16);
            unsigned w1 = (unsigned)f2bf(va.y) | ((unsigned)f2bf(vb.y) << 16);
            *(uint2*)(&tile[c0 >> 1][px2 << 1]) = make_uint2(w0, w1);
        }
        __syncthreads();
#pragma unroll
        for (int it = 0; it < 16; ++it) {
            int idx = it * 256 + tid;
            int cq5 = idx & 31;          // 4-channel group
            int pos = idx >> 5;          // 0..127
            int posn = min(pos + 1, 127);
            unsigned t0 = tile[2 * cq5][pos], t0n = tile[2 * cq5][posn];
            unsigned t1 = tile[2 * cq5 + 1][pos], t1n = tile[2 * cq5 + 1][posn];
            uint4 o;
            o.x = (t0 & 0xffffu) | (t0n << 16);
            o.y = (t0 >> 16) | (t0n & 0xffff0000u);
            o.z = (t1 & 0xffffu) | (t1n << 16);
            o.w = (t1 >> 16) | (t1n & 0xffff0000u);
            *(uint4*)(xpair + (((size_t)(b << 14) + (h << 7) + pos) << 7) + (cq5 << 2)) = o;
        }
    } else if (bid < 656) {
        int t = (bid - 512) * 256 + tid;
        if (t < Cch * CK) {
            int oc = t / CK;
            int rem = t % CK;
            int k = rem >> 6, c = rem & 63;
            wbf[t] = f2bf(w[(oc * Cch + c) * 9 + k]);
        }
    } else {
        int t = (bid - 656) * 256 + tid;
        if (t < 9 * 32 * 128) {
            int ci = t & 127, ocp = (t >> 7) & 31, tap = t >> 12;
            w9[t] = (ocp < NOFF) ? f2bf(wo[(ocp * 128 + ci) * 9 + tap]) : (unsigned short)0;
        }
    }
}

// ---------------------------------------------------------------------------
// Fused kernel, 32-px blocks (2 sub-strips). Block = (b, h, 32-px strip).
// A0 : stage tile3 from xpair lows -- loads batched into 13 regs, then writes.
// A1 : offset MFMA; wave (to,kh) runs BOTH sub-strips reusing w9 fragments.
// FIN: kh==0 waves finalize offsets + corner weights/meta for both strips.
// B  : gather; per strip ALL 18 uint4 loads issued before any pack (wide ILP).
// B1 : deform MFMA; wave = oc-tile, both sub-strips reuse wbf fragments.
__global__ __launch_bounds__(256, 3) void fused_align(
        const unsigned* __restrict__ xpair,
        const unsigned short* __restrict__ w9,
        const unsigned short* __restrict__ wbf,
        const float* __restrict__ bias,
        float* __restrict__ out) {
    __shared__ union {
        unsigned short tile3[3 * 34 * 128];         // 26.1 KB
        unsigned short smp[32][CKPAD];              // 37.1 KB
    } u;
    __shared__ float red[2][2][64][4];              // [strip][to] 4 KB
    __shared__ float4 wts[288];                     // 4.6 KB
    __shared__ int2 meta[288];                      // 2.3 KB

    int bi0 = blockIdx.x;
    int bi = ((bi0 & 7) << 8) | (bi0 >> 3);   // XCD swizzle (2048 = 8*256)
    int b = bi >> 9;
    int rem = bi & 511;
    int h = rem >> 2;
    int w0 = (rem & 3) << 5;
    int tid = threadIdx.x;
    int wv = tid >> 6, lane = tid & 63;
    int to = wv & 1;          // oc tile (offset conv)
    int kh = wv >> 1;         // ci half (0: x, 1: ref)
    int r16 = lane & 15;
    int g = lane >> 4;

    const unsigned* xp32 = xpair + ((size_t)b << 21);   // b * 16384 pos * 128 u32

    float bias4[4] = {0.f, 0.f, 0.f, 0.f};
    if (kh == 0) {
#pragma unroll
        for (int r = 0; r < 4; ++r) {
            int oc = to * 16 + g * 4 + r;
            if (oc < NOFF) bias4[r] = bias[oc];
        }
    }

    // ---- Phase A0: 13 loads batched into registers, then 13 LDS writes ----
    {
        uint4 qa[13];
#pragma unroll
        for (int it = 0; it < 13; ++it) {
            int idx = it * 256 + tid;
            qa[it] = make_uint4(0u, 0u, 0u, 0u);
            if (idx < 3264) {
                int cq4 = idx & 31;              // 4-channel group
                int pos = idx >> 5;              // row*34 + xx
                int row = pos / 34, xx = pos % 34;
                int yy = h + row - 1, xg = w0 + xx - 1;
                if ((unsigned)yy < (unsigned)Hh && (unsigned)xg < (unsigned)Ww)
                    qa[it] = *(const uint4*)(xp32 + (((yy << 7) + xg) << 7) + (cq4 << 2));
            }
        }
#pragma unroll
        for (int it = 0; it < 13; ++it) {
            int idx = it * 256 + tid;
            if (idx < 3264) {
                int cq4 = idx & 31;
                int pos = idx >> 5;
                int xx = pos % 34;
                unsigned p0v = (qa[it].x & 0xffffu) | (qa[it].y << 16);
                unsigned p1v = (qa[it].z & 0xffffu) | (qa[it].w << 16);
                int ci0 = cq4 << 2;
                *(uint2*)(&u.tile3[(pos << 7) + (ci0 ^ ((xx & 7) << 3))]) =
                    make_uint2(p0v, p1v);
            }
        }
    }
    __syncthreads();

    // ---- Phase A1: offset conv MFMA; both strips share w9 fragments ----
    floatx4 accA0 = {0.f, 0.f, 0.f, 0.f};
    floatx4 accA1 = {0.f, 0.f, 0.f, 0.f};
#pragma unroll
    for (int tap = 0; tap < 9; ++tap) {
        int dy = tap / 3, dx = tap % 3;
        const unsigned short* arow = w9 + ((size_t)(tap * 32 + to * 16 + r16) << 7) + kh * 64;
        short8 a0 = *(const short8*)(arow + g * 8);          // k-group g, kk=0
        short8 a1 = *(const short8*)(arow + 32 + g * 8);     // k-group g, kk=1
#pragma unroll
        for (int s = 0; s < 2; ++s) {
            int xxr = r16 + dx + s * 16;                     // 0..33
            const unsigned short* brow = &u.tile3[(dy * 34 + xxr) << 7];
            int sw = (xxr & 7) << 3;
            int cb0 = kh * 64 + g * 8;
            short8 bb0 = *(const short8*)(brow + (cb0 ^ sw));
            short8 bb1 = *(const short8*)(brow + ((cb0 + 32) ^ sw));
            if (s == 0) {
                accA0 = __builtin_amdgcn_mfma_f32_16x16x32_bf16(a0, bb0, accA0, 0, 0, 0);
                accA0 = __builtin_amdgcn_mfma_f32_16x16x32_bf16(a1, bb1, accA0, 0, 0, 0);
            } else {
                accA1 = __builtin_amdgcn_mfma_f32_16x16x32_bf16(a0, bb0, accA1, 0, 0, 0);
                accA1 = __builtin_amdgcn_mfma_f32_16x16x32_bf16(a1, bb1, accA1, 0, 0, 0);
            }
        }
    }
    if (kh == 1) {
#pragma unroll
        for (int r = 0; r < 4; ++r) { red[0][to][lane][r] = accA0[r]; red[1][to][lane][r] = accA1[r]; }
    }
    __syncthreads();

    // ---- FIN: offsets -> corner weights + row byte-offsets, both strips ----
    if (kh == 0 && (to == 0 || g == 0)) {
        int ntap = (to == 0) ? 2 : 1;
        int kbase = (to * 16 + g * 4) >> 1;
#pragma unroll
        for (int s = 0; s < 2; ++s) {
            float vout[4];
#pragma unroll
            for (int r = 0; r < 4; ++r) {
                float v = (s == 0 ? accA0[r] : accA1[r]) + red[s][to][lane][r] + bias4[r];
                vout[r] = fminf(fmaxf(v, -10.0f), 10.0f);
            }
            int p = s * 16 + r16;
#pragma unroll
            for (int t = 0; t < 2; ++t) {
                if (t < ntap) {
                    int k = kbase + t;
                    float dyo = vout[2 * t], dxo = vout[2 * t + 1];
                    int ky = k / 3, kx = k % 3;
                    float ys = (float)(h - 1 + ky) + dyo;
                    float xs = (float)(w0 + p - 1 + kx) + dxo;
                    float fy = floorf(ys), fx = floorf(xs);
                    int iy0 = (int)fy, ix0 = (int)fx;
                    float ty = ys - fy, tx = xs - fx;
                    float wy0 = (1.f - ty) * (((unsigned)iy0 < (unsigned)Hh) ? 1.f : 0.f);
                    float wy1 = ty         * (((unsigned)(iy0 + 1) < (unsigned)Hh) ? 1.f : 0.f);
                    float wx0 = (1.f - tx) * (((unsigned)ix0 < (unsigned)Ww) ? 1.f : 0.f);
                    float wx1 = tx         * (((unsigned)(ix0 + 1) < (unsigned)Ww) ? 1.f : 0.f);
                    int ixb  = min(max(ix0, 0), Ww - 2);
                    int iy0c = min(max(iy0, 0), Hh - 1);
                    int iy1c = min(max(iy0 + 1, 0), Hh - 1);
                    bool s0v = (min(max(ix0, 0), Ww - 1) != ixb);
                    bool s1v = (min(max(ix0 + 1, 0), Ww - 1) != ixb);
                    float w00 = wy0 * wx0, w01 = wy0 * wx1, w10 = wy1 * wx0, w11 = wy1 * wx1;
                    float A  = (s0v ? 0.f : w00) + (s1v ? 0.f : w01);   // (y0, ixb)
                    float Bw = (s0v ? w00 : 0.f) + (s1v ? w01 : 0.f);   // (y0, ixb+1)
                    float Cw = (s0v ? 0.f : w10) + (s1v ? 0.f : w11);   // (y1, ixb)
                    float Dw = (s0v ? w10 : 0.f) + (s1v ? w11 : 0.f);   // (y1, ixb+1)
                    wts[p * 9 + k] = make_float4(A, Bw, Cw, Dw);
                    meta[p * 9 + k] = make_int2(((iy0c << 7) + ixb) << 9,
                                                ((iy1c << 7) + ixb) << 9);
                }
            }
        }
    }
    __syncthreads();   // wts/meta ready; tile3 dead -> smp may overwrite

    // ---- Phase B: gather; per strip all 18 loads in flight before packs ----
    {
        int p0 = tid >> 4, cq = tid & 15;
        const char* xbB = (const char*)xpair + ((size_t)b << 23) + cq * 16;
#pragma unroll
        for (int s = 0; s < 2; ++s) {
            int p = p0 + s * 16;
            uint4 q0[9], q1[9];
#pragma unroll
            for (int k = 0; k < 9; ++k) {
                int2 mm = meta[p * 9 + k];
                q0[k] = *(const uint4*)(xbB + mm.x);
                q1[k] = *(const uint4*)(xbB + mm.y);
            }
#pragma unroll
            for (int k = 0; k < 9; ++k) {
                float4 wt = wts[p * 9 + k];
                uint4 qa = q0[k], qb = q1[k];
                float s0 = bflo(qa.x)*wt.x + bfhi(qa.x)*wt.y + bflo(qb.x)*wt.z + bfhi(qb.x)*wt.w;
                float s1 = bflo(qa.y)*wt.x + bfhi(qa.y)*wt.y + bflo(qb.y)*wt.z + bfhi(qb.y)*wt.w;
                float s2 = bflo(qa.z)*wt.x + bfhi(qa.z)*wt.y + bflo(qb.z)*wt.z + bfhi(qb.z)*wt.w;
                float s3 = bflo(qa.w)*wt.x + bfhi(qa.w)*wt.y + bflo(qb.w)*wt.z + bfhi(qb.w)*wt.w;
                *(uint2*)(&u.smp[p][k * 64 + cq * 4]) =
                    make_uint2(cvtpk(s0, s1), cvtpk(s2, s3));
            }
        }
    }
    __syncthreads();

    // ---- Phase B1: deform MFMA; both strips share wbf fragments ----
    {
        floatx4 acc0 = {0.f, 0.f, 0.f, 0.f};
        floatx4 acc1 = {0.f, 0.f, 0.f, 0.f};
        const short8* ap = (const short8*)(wbf + (size_t)(wv * 16 + r16) * CK + g * 8);
        const unsigned short* bb0 = &u.smp[r16][g * 8];
        const unsigned short* bb1 = &u.smp[16 + r16][g * 8];
#pragma unroll
        for (int kk = 0; kk < 18; ++kk) {
            short8 a = ap[kk * 4];
            short8 v0 = *(const short8*)(bb0 + kk * 32);
            short8 v1 = *(const short8*)(bb1 + kk * 32);
            acc0 = __builtin_amdgcn_mfma_f32_16x16x32_bf16(a, v0, acc0, 0, 0, 0);
            acc1 = __builtin_amdgcn_mfma_f32_16x16x32_bf16(a, v1, acc1, 0, 0, 0);
        }
        size_t obase = ((size_t)(b * Cch + wv * 16 + g * 4)) << 14;
        int hw = (h << 7) + w0 + r16;
#pragma unroll
        for (int r = 0; r < 4; ++r) {
            out[obase + ((size_t)r << 14) + hw] = acc0[r];
            out[obase + ((size_t)r << 14) + hw + 16] = acc1[r];
        }
    }
}

// ---------------------------------------------------------------------------
extern "C" void kernel_launch(void* const* d_in, const int* in_sizes, int n_in,
                              void* d_out, int out_size, void* d_ws, size_t ws_size,
                              hipStream_t stream) {
    const float* x      = (const float*)d_in[0];
    const float* ref    = (const float*)d_in[1];
    const float* wo     = (const float*)d_in[2];
    const float* bias   = (const float*)d_in[3];
    const float* weight = (const float*)d_in[4];
    float* out = (float*)d_out;

    unsigned short* w9  = (unsigned short*)d_ws;                      // 72 KB
    unsigned short* wbf = (unsigned short*)((char*)d_ws + 262144);    // 72 KB
    unsigned* xpair     = (unsigned*)((char*)d_ws + 524288);          // 33.5 MB

    hipLaunchKernelGGL(prep, dim3(800), dim3(256), 0, stream,
                       x, ref, wo, weight, xpair, w9, wbf);
    hipLaunchKernelGGL(fused_align, dim3(2048), dim3(256), 0, stream,
                       xpair, w9, wbf, bias, out);
}

// Round 17
// 75.962 us; speedup vs baseline: 1.2513x; 1.0487x over previous
//
#include <hip/hip_runtime.h>

#define Bsz 4
#define Cch 64
#define Hh 128
#define Ww 128
#define NOFF 18      // 2*3*3 offset channels
#define CK 576       // 64*9 reduction length for deform einsum (K = k*64 + c)
#define CKPAD 580    // smp row stride (bf16): 1160B

typedef __attribute__((ext_vector_type(8))) short short8;
typedef __attribute__((ext_vector_type(4))) float floatx4;

__device__ __forceinline__ unsigned short f2bf(float f) {
    union { float f; unsigned u; } v; v.f = f;
    unsigned r = v.u + 0x7fff + ((v.u >> 16) & 1);   // round-to-nearest-even
    return (unsigned short)(r >> 16);
}
__device__ __forceinline__ float bflo(unsigned d) {
    union { unsigned u; float f; } v; v.u = d << 16; return v.f;
}
__device__ __forceinline__ float bfhi(unsigned d) {
    union { unsigned u; float f; } v; v.u = d & 0xffff0000u; return v.f;
}
__device__ __forceinline__ unsigned cvtpk(float lo, float hi) {   // {bf16(lo), bf16(hi)<<16}
    unsigned r;
    asm("v_cvt_pk_bf16_f32 %0, %1, %2" : "=v"(r) : "v"(lo), "v"(hi));
    return r;
}
// Batched gather load: asm so the compiler cannot fuse it with consumers.
// MUST be followed (after all loads of the batch) by
//   asm volatile("s_waitcnt vmcnt(0)") + __builtin_amdgcn_sched_barrier(0)
// before any use of the results (rule: compiler doesn't track asm vmcnt).
__device__ __forceinline__ uint4 gld4(const void* p) {
    uint4 q;
    asm volatile("global_load_dwordx4 %0, %1, off" : "=v"(q) : "v"(p) : "memory");
    return q;
}

// ---------------------------------------------------------------------------
// Prep kernel.
//   blocks 0..511  : build xpair[b][h*w][128ch] u32 = {bf16 v(pos,c), bf16 v(pos+1,c)}
//   blocks 512..655: deform weight w[oc][c][tap] -> wbf[oc][tap*64+c] bf16
//   blocks 656..799: offset weight wo[oc][ci][tap] -> w9[tap][32ocp][128ci] bf16
__global__ __launch_bounds__(256) void prep(const float* __restrict__ x,
                                            const float* __restrict__ ref,
                                            const float* __restrict__ wo,
                                            const float* __restrict__ w,
                                            unsigned* __restrict__ xpair,
                                            unsigned short* __restrict__ w9,
                                            unsigned short* __restrict__ wbf) {
    __shared__ unsigned tile[64][130];   // [cpair][px]; stride 130 u32
    int bid = blockIdx.x;
    int tid = threadIdx.x;
    if (bid < 512) {
        int b = bid >> 7;
        int h = bid & 127;
        int px2 = tid & 63;              // pixel pair: px = 2*px2, 2*px2+1
        int cg = tid >> 6;               // 32-channel group
        const float* xb = x + ((size_t)b << 20) + (h << 7) + (px2 << 1);
        const float* rb = ref + ((size_t)b << 20) + (h << 7) + (px2 << 1);
#pragma unroll
        for (int j = 0; j < 16; ++j) {
            int c0 = cg * 32 + 2 * j;
            const float* s = (c0 < 64) ? xb : rb;
            int cl = c0 & 63;
            float2 va = *(const float2*)(s + ((size_t)cl << 14));
            float2 vb = *(const float2*)(s + ((size_t)(cl + 1) << 14));
            unsigned w0 = (unsigned)f2bf(va.x) | ((unsigned)f2bf(vb.x) << 16);
            unsigned w1 = (unsigned)f2bf(va.y) | ((unsigned)f2bf(vb.y) << 16);
            *(uint2*)(&tile[c0 >> 1][px2 << 1]) = make_uint2(w0, w1);
        }
        __syncthreads();
#pragma unroll
        for (int it = 0; it < 16; ++it) {
            int idx = it * 256 + tid;
            int cq5 = idx & 31;          // 4-channel group
            int pos = idx >> 5;          // 0..127
            int posn = min(pos + 1, 127);
            unsigned t0 = tile[2 * cq5][pos], t0n = tile[2 * cq5][posn];
            unsigned t1 = tile[2 * cq5 + 1][pos], t1n = tile[2 * cq5 + 1][posn];
            uint4 o;
            o.x = (t0 & 0xffffu) | (t0n << 16);
            o.y = (t0 >> 16) | (t0n & 0xffff0000u);
            o.z = (t1 & 0xffffu) | (t1n << 16);
            o.w = (t1 >> 16) | (t1n & 0xffff0000u);
            *(uint4*)(xpair + (((size_t)(b << 14) + (h << 7) + pos) << 7) + (cq5 << 2)) = o;
        }
    } else if (bid < 656) {
        int t = (bid - 512) * 256 + tid;
        if (t < Cch * CK) {
            int oc = t / CK;
            int rem = t % CK;
            int k = rem >> 6, c = rem & 63;
            wbf[t] = f2bf(w[(oc * Cch + c) * 9 + k]);
        }
    } else {
        int t = (bid - 656) * 256 + tid;
        if (t < 9 * 32 * 128) {
            int ci = t & 127, ocp = (t >> 7) & 31, tap = t >> 12;
            w9[t] = (ocp < NOFF) ? f2bf(wo[(ocp * 128 + ci) * 9 + tap]) : (unsigned short)0;
        }
    }
}

// ---------------------------------------------------------------------------
// Fused kernel, 32-px blocks (2 sub-strips). Block = (b, h, 32-px strip).
// A0 : 13 asm-batched loads -> vmcnt(0) -> 13 LDS writes (1 round-trip).
// A1 : offset MFMA; wave (to,kh) runs BOTH sub-strips reusing w9 fragments.
// FIN: kh==0 waves finalize offsets + corner weights/meta for both strips.
// B  : per strip 18 asm-batched gather loads -> vmcnt(0) -> 9 packs.
// B1 : deform MFMA; wave = oc-tile, both sub-strips reuse wbf fragments.
__global__ __launch_bounds__(256, 3) void fused_align(
        const unsigned* __restrict__ xpair,
        const unsigned short* __restrict__ w9,
        const unsigned short* __restrict__ wbf,
        const float* __restrict__ bias,
        float* __restrict__ out) {
    __shared__ union {
        unsigned short tile3[3 * 34 * 128];         // 26.1 KB
        unsigned short smp[32][CKPAD];              // 37.1 KB
    } u;
    __shared__ float red[2][2][64][4];              // [strip][to] 4 KB
    __shared__ float4 wts[288];                     // 4.6 KB
    __shared__ int2 meta[288];                      // 2.3 KB

    int bi0 = blockIdx.x;
    int bi = ((bi0 & 7) << 8) | (bi0 >> 3);   // XCD swizzle (2048 = 8*256)
    int b = bi >> 9;
    int rem = bi & 511;
    int h = rem >> 2;
    int w0 = (rem & 3) << 5;
    int tid = threadIdx.x;
    int wv = tid >> 6, lane = tid & 63;
    int to = wv & 1;          // oc tile (offset conv)
    int kh = wv >> 1;         // ci half (0: x, 1: ref)
    int r16 = lane & 15;
    int g = lane >> 4;

    const unsigned* xp32 = xpair + ((size_t)b << 21);   // b * 16384 pos * 128 u32

    float bias4[4] = {0.f, 0.f, 0.f, 0.f};
    if (kh == 0) {
#pragma unroll
        for (int r = 0; r < 4; ++r) {
            int oc = to * 16 + g * 4 + r;
            if (oc < NOFF) bias4[r] = bias[oc];
        }
    }

    // ---- Phase A0: 13 asm loads in flight -> vmcnt(0) -> LDS writes ----
    {
        uint4 qa[13];
        bool val[13];
#pragma unroll
        for (int it = 0; it < 13; ++it) {
            int idx = it * 256 + tid;
            int idc = (idx < 3264) ? idx : 0;
            int cq4 = idc & 31;              // 4-channel group
            int pos = idc >> 5;              // row*34 + xx
            int row = pos / 34, xx = pos % 34;
            int yy = h + row - 1, xg = w0 + xx - 1;
            bool v = ((unsigned)yy < (unsigned)Hh) && ((unsigned)xg < (unsigned)Ww);
            val[it] = v;
            const unsigned* ap = xp32 + (((yy << 7) + xg) << 7) + (cq4 << 2);
            qa[it] = gld4(v ? (const void*)ap : (const void*)xp32);
        }
        asm volatile("s_waitcnt vmcnt(0)" ::: "memory");
        __builtin_amdgcn_sched_barrier(0);
#pragma unroll
        for (int it = 0; it < 13; ++it) {
            int idx = it * 256 + tid;
            if (idx < 3264) {
                int cq4 = idx & 31;
                int pos = idx >> 5;
                int xx = pos % 34;
                uint4 q = val[it] ? qa[it] : make_uint4(0u, 0u, 0u, 0u);
                unsigned p0v = (q.x & 0xffffu) | (q.y << 16);
                unsigned p1v = (q.z & 0xffffu) | (q.w << 16);
                int ci0 = cq4 << 2;
                *(uint2*)(&u.tile3[(pos << 7) + (ci0 ^ ((xx & 7) << 3))]) =
                    make_uint2(p0v, p1v);
            }
        }
    }
    __syncthreads();

    // ---- Phase A1: offset conv MFMA; both strips share w9 fragments ----
    floatx4 accA0 = {0.f, 0.f, 0.f, 0.f};
    floatx4 accA1 = {0.f, 0.f, 0.f, 0.f};
#pragma unroll
    for (int tap = 0; tap < 9; ++tap) {
        int dy = tap / 3, dx = tap % 3;
        const unsigned short* arow = w9 + ((size_t)(tap * 32 + to * 16 + r16) << 7) + kh * 64;
        short8 a0 = *(const short8*)(arow + g * 8);          // k-group g, kk=0
        short8 a1 = *(const short8*)(arow + 32 + g * 8);     // k-group g, kk=1
#pragma unroll
        for (int s = 0; s < 2; ++s) {
            int xxr = r16 + dx + s * 16;                     // 0..33
            const unsigned short* brow = &u.tile3[(dy * 34 + xxr) << 7];
            int sw = (xxr & 7) << 3;
            int cb0 = kh * 64 + g * 8;
            short8 bb0 = *(const short8*)(brow + (cb0 ^ sw));
            short8 bb1 = *(const short8*)(brow + ((cb0 + 32) ^ sw));
            if (s == 0) {
                accA0 = __builtin_amdgcn_mfma_f32_16x16x32_bf16(a0, bb0, accA0, 0, 0, 0);
                accA0 = __builtin_amdgcn_mfma_f32_16x16x32_bf16(a1, bb1, accA0, 0, 0, 0);
            } else {
                accA1 = __builtin_amdgcn_mfma_f32_16x16x32_bf16(a0, bb0, accA1, 0, 0, 0);
                accA1 = __builtin_amdgcn_mfma_f32_16x16x32_bf16(a1, bb1, accA1, 0, 0, 0);
            }
        }
    }
    if (kh == 1) {
#pragma unroll
        for (int r = 0; r < 4; ++r) { red[0][to][lane][r] = accA0[r]; red[1][to][lane][r] = accA1[r]; }
    }
    __syncthreads();

    // ---- FIN: offsets -> corner weights + row byte-offsets, both strips ----
    if (kh == 0 && (to == 0 || g == 0)) {
        int ntap = (to == 0) ? 2 : 1;
        int kbase = (to * 16 + g * 4) >> 1;
#pragma unroll
        for (int s = 0; s < 2; ++s) {
            float vout[4];
#pragma unroll
            for (int r = 0; r < 4; ++r) {
                float v = (s == 0 ? accA0[r] : accA1[r]) + red[s][to][lane][r] + bias4[r];
                vout[r] = fminf(fmaxf(v, -10.0f), 10.0f);
            }
            int p = s * 16 + r16;
#pragma unroll
            for (int t = 0; t < 2; ++t) {
                if (t < ntap) {
                    int k = kbase + t;
                    float dyo = vout[2 * t], dxo = vout[2 * t + 1];
                    int ky = k / 3, kx = k % 3;
                    float ys = (float)(h - 1 + ky) + dyo;
                    float xs = (float)(w0 + p - 1 + kx) + dxo;
                    float fy = floorf(ys), fx = floorf(xs);
                    int iy0 = (int)fy, ix0 = (int)fx;
                    float ty = ys - fy, tx = xs - fx;
                    float wy0 = (1.f - ty) * (((unsigned)iy0 < (unsigned)Hh) ? 1.f : 0.f);
                    float wy1 = ty         * (((unsigned)(iy0 + 1) < (unsigned)Hh) ? 1.f : 0.f);
                    float wx0 = (1.f - tx) * (((unsigned)ix0 < (unsigned)Ww) ? 1.f : 0.f);
                    float wx1 = tx         * (((unsigned)(ix0 + 1) < (unsigned)Ww) ? 1.f : 0.f);
                    int ixb  = min(max(ix0, 0), Ww - 2);
                    int iy0c = min(max(iy0, 0), Hh - 1);
                    int iy1c = min(max(iy0 + 1, 0), Hh - 1);
                    bool s0v = (min(max(ix0, 0), Ww - 1) != ixb);
                    bool s1v = (min(max(ix0 + 1, 0), Ww - 1) != ixb);
                    float w00 = wy0 * wx0, w01 = wy0 * wx1, w10 = wy1 * wx0, w11 = wy1 * wx1;
                    float A  = (s0v ? 0.f : w00) + (s1v ? 0.f : w01);   // (y0, ixb)
                    float Bw = (s0v ? w00 : 0.f) + (s1v ? w01 : 0.f);   // (y0, ixb+1)
                    float Cw = (s0v ? 0.f : w10) + (s1v ? 0.f : w11);   // (y1, ixb)
                    float Dw = (s0v ? w10 : 0.f) + (s1v ? w11 : 0.f);   // (y1, ixb+1)
                    wts[p * 9 + k] = make_float4(A, Bw, Cw, Dw);
                    meta[p * 9 + k] = make_int2(((iy0c << 7) + ixb) << 9,
                                                ((iy1c << 7) + ixb) << 9);
                }
            }
        }
    }
    __syncthreads();   // wts/meta ready; tile3 dead -> smp may overwrite

    // ---- Phase B: per strip, 18 asm loads in flight -> vmcnt(0) -> packs ----
    {
        int p0 = tid >> 4, cq = tid & 15;
        const char* xbB = (const char*)xpair + ((size_t)b << 23) + cq * 16;
#pragma unroll
        for (int s = 0; s < 2; ++s) {
            int p = p0 + s * 16;
            uint4 q0[9], q1[9];
            float4 wt[9];
#pragma unroll
            for (int k = 0; k < 9; ++k) {
                int2 mm = meta[p * 9 + k];
                wt[k] = wts[p * 9 + k];
                q0[k] = gld4(xbB + mm.x);
                q1[k] = gld4(xbB + mm.y);
            }
            asm volatile("s_waitcnt vmcnt(0)" ::: "memory");
            __builtin_amdgcn_sched_barrier(0);
#pragma unroll
            for (int k = 0; k < 9; ++k) {
                uint4 qa = q0[k], qb = q1[k];
                float4 w = wt[k];
                float s0 = bflo(qa.x)*w.x + bfhi(qa.x)*w.y + bflo(qb.x)*w.z + bfhi(qb.x)*w.w;
                float s1 = bflo(qa.y)*w.x + bfhi(qa.y)*w.y + bflo(qb.y)*w.z + bfhi(qb.y)*w.w;
                float s2 = bflo(qa.z)*w.x + bfhi(qa.z)*w.y + bflo(qb.z)*w.z + bfhi(qb.z)*w.w;
                float s3 = bflo(qa.w)*w.x + bfhi(qa.w)*w.y + bflo(qb.w)*w.z + bfhi(qb.w)*w.w;
                *(uint2*)(&u.smp[p][k * 64 + cq * 4]) =
                    make_uint2(cvtpk(s0, s1), cvtpk(s2, s3));
            }
        }
    }
    __syncthreads();

    // ---- Phase B1: deform MFMA; both strips share wbf fragments ----
    {
        floatx4 acc0 = {0.f, 0.f, 0.f, 0.f};
        floatx4 acc1 = {0.f, 0.f, 0.f, 0.f};
        const short8* ap = (const short8*)(wbf + (size_t)(wv * 16 + r16) * CK + g * 8);
        const unsigned short* bb0 = &u.smp[r16][g * 8];
        const unsigned short* bb1 = &u.smp[16 + r16][g * 8];
#pragma unroll
        for (int kk = 0; kk < 18; ++kk) {
            short8 a = ap[kk * 4];
            short8 v0 = *(const short8*)(bb0 + kk * 32);
            short8 v1 = *(const short8*)(bb1 + kk * 32);
            acc0 = __builtin_amdgcn_mfma_f32_16x16x32_bf16(a, v0, acc0, 0, 0, 0);
            acc1 = __builtin_amdgcn_mfma_f32_16x16x32_bf16(a, v1, acc1, 0, 0, 0);
        }
        size_t obase = ((size_t)(b * Cch + wv * 16 + g * 4)) << 14;
        int hw = (h << 7) + w0 + r16;
#pragma unroll
        for (int r = 0; r < 4; ++r) {
            out[obase + ((size_t)r << 14) + hw] = acc0[r];
            out[obase + ((size_t)r << 14) + hw + 16] = acc1[r];
        }
    }
}

// ---------------------------------------------------------------------------
extern "C" void kernel_launch(void* const* d_in, const int* in_sizes, int n_in,
                              void* d_out, int out_size, void* d_ws, size_t ws_size,
                              hipStream_t stream) {
    const float* x      = (const float*)d_in[0];
    const float* ref    = (const float*)d_in[1];
    const float* wo     = (const float*)d_in[2];
    const float* bias   = (const float*)d_in[3];
    const float* weight = (const float*)d_in[4];
    float* out = (float*)d_out;

    unsigned short* w9  = (unsigned short*)d_ws;                      // 72 KB
    unsigned short* wbf = (unsigned short*)((char*)d_ws + 262144);    // 72 KB
    unsigned* xpair     = (unsigned*)((char*)d_ws + 524288);          // 33.5 MB

    hipLaunchKernelGGL(prep, dim3(800), dim3(256), 0, stream,
                       x, ref, wo, weight, xpair, w9, wbf);
    hipLaunchKernelGGL(fused_align, dim3(2048), dim3(256), 0, stream,
                       xpair, w9, wbf, bias, out);
}